// Round 7
// baseline (324.167 us; speedup 1.0000x reference)
//
#include <hip/hip_runtime.h>
#include <stdint.h>

// GCN layer: out = prelu(W @ segsum(A_val * h[A_col] -> A_row) + b, act_a)
//            h   = prelu(Wr @ AX + br, g_a)
// R6: GEMM2 fused into SpMM. R7: occ 61% @ 80.6us (best spmm). R8 FAILED:
// global atomic scatter 145us (contention + 7x write-allocate on random 8B
// stores). R10 DECISIVE: beyond-L2 fetch pinned 2.0-2.25 TB/s across 4 spmm
// structures -> random-line fetch CEILING; h-miss ~165MB == compulsory floor
// (8 XCDs x 86% col coverage x 25.6MB). spmm AT its roofline (~79us).
// R11 FAILED: threadfence last-block scan = 418us (device-scope fence
// flushes XCD L2 per block). LESSON: grid deps -> dispatch boundaries only.
// R12: hist fused into GEMM dispatch = neutral (hist was already cheap).
// Budget: spmm 79 + ~208us hidden. Prime suspect: scatter's write-allocate
// (NBLK=256 -> 2 edges = 16B per bucket per block, 800K sub-line stores).
// R13: GROUPED SCATTER: SCTB=64 blocks x GRP=4 chunks -> ~8 edges = 64B
// (full line) per bucket per block. Cursor init from hist_g[b][s*GRP] is
// exact (exclusive scan gives contiguous dest range for the chunk group).

typedef _Float16 half8 __attribute__((ext_vector_type(8)));
typedef _Float16 half4 __attribute__((ext_vector_type(4)));
typedef _Float16 half2v __attribute__((ext_vector_type(2)));
typedef float floatx4 __attribute__((ext_vector_type(4)));

#define LDK 136        // GEMM LDS row stride in halfs: 128 + 8
#define SHIFT 5        // 32 rows per bucket
#define NBMAX 3200     // >= ceil(100000/32) = 3125
#define NBLK 256       // hist chunks
#define SCTB 64        // scatter blocks
#define GRP (NBLK / SCTB)  // 4 chunks per scatter block
#define SCT 1024       // scatter threads per block
#define CAP 1024       // LDS edge capacity per sort chunk (max bucket ~650 expected)

// ------ fused GEMM1 + hist: blocks [0,NBLK) do the bucket histogram;
// ------ blocks [NBLK, NBLK+gemmB) do h = prelu(AX@Wr^T + br). No dependency.
__global__ __launch_bounds__(256, 2)
void gemm_hist(const float* __restrict__ X, const float* __restrict__ Wr,
               const float* __restrict__ bias, const float* __restrict__ alpha_p,
               _Float16* __restrict__ out, int N,
               const int* __restrict__ rows, int* __restrict__ hist_g,
               int E, int chunk, int NB,
               const float* __restrict__ W, _Float16* __restrict__ W16)
{
    __shared__ _Float16 Xs[128 * LDK];
    __shared__ _Float16 Ws[128 * LDK];
    const int tid = threadIdx.x;

    if (blockIdx.x < NBLK) {
        // ---------------- histogram path (layout: hist_g[b*NBLK + blk]) ----
        const int hb = blockIdx.x;
        int* lh = (int*)Xs;                       // alias LDS (12.8KB of 34.8KB)
        if (hb == 0) {
#pragma unroll
            for (int j = 0; j < 64; ++j)          // W fp32 -> f16 (16384 elems)
                W16[tid + j * 256] = (_Float16)W[tid + j * 256];
        }
        for (int i = tid; i < NB; i += 256) lh[i] = 0;
        __syncthreads();
        int s = hb * chunk, e = min(E, s + chunk);
        for (int i = s + tid; i < e; i += 256)
            atomicAdd(&lh[rows[i] >> SHIFT], 1);
        __syncthreads();
        for (int b = tid; b < NB; b += 256)
            hist_g[b * NBLK + hb] = lh[b];
        return;
    }

    // ---------------- GEMM path ----------------
    const int bm  = (blockIdx.x - NBLK) * 128;
    const float alpha = *alpha_p;

#pragma unroll
    for (int i = 0; i < 16; ++i) {
        int c   = tid + i * 256;
        int row = c >> 5;
        int coff = (c & 31) * 4;
        float4 f = *(const float4*)(Wr + row * 128 + coff);
        half4 hv = { (_Float16)f.x, (_Float16)f.y, (_Float16)f.z, (_Float16)f.w };
        *(half4*)(&Ws[row * LDK + coff]) = hv;
    }
#pragma unroll
    for (int i = 0; i < 16; ++i) {
        int c   = tid + i * 256;
        int row = c >> 5;
        int coff = (c & 31) * 4;
        int grow = bm + row;
        half4 hv = {};
        if (grow < N) {
            float4 f = *(const float4*)(X + (size_t)grow * 128 + coff);
            hv[0] = (_Float16)f.x; hv[1] = (_Float16)f.y;
            hv[2] = (_Float16)f.z; hv[3] = (_Float16)f.w;
        }
        *(half4*)(&Xs[row * LDK + coff]) = hv;
    }
    __syncthreads();

    const int wave = tid >> 6;
    const int lane = tid & 63;
    const int l15  = lane & 15;
    const int quad = lane >> 4;

    floatx4 acc[2][8] = {};
#pragma unroll
    for (int k0 = 0; k0 < 128; k0 += 32) {
        half8 a0 = *(const half8*)(&Xs[(wave * 32 +      l15) * LDK + k0 + quad * 8]);
        half8 a1 = *(const half8*)(&Xs[(wave * 32 + 16 + l15) * LDK + k0 + quad * 8]);
        half8 b[8];
#pragma unroll
        for (int n = 0; n < 8; ++n)
            b[n] = *(const half8*)(&Ws[(n * 16 + l15) * LDK + k0 + quad * 8]);
#pragma unroll
        for (int n = 0; n < 8; ++n) {
            acc[0][n] = __builtin_amdgcn_mfma_f32_16x16x32_f16(a0, b[n], acc[0][n], 0, 0, 0);
            acc[1][n] = __builtin_amdgcn_mfma_f32_16x16x32_f16(a1, b[n], acc[1][n], 0, 0, 0);
        }
    }

#pragma unroll
    for (int mt = 0; mt < 2; ++mt) {
#pragma unroll
        for (int n = 0; n < 8; ++n) {
#pragma unroll
            for (int r = 0; r < 4; ++r) {
                int row = bm + wave * 32 + mt * 16 + quad * 4 + r;
                int col = n * 16 + l15;
                if (row < N) {
                    float v = acc[mt][n][r] + bias[col];
                    v = (v >= 0.f) ? v : alpha * v;
                    out[(size_t)row * 128 + col] = (_Float16)v;
                }
            }
        }
    }
}

// per-bucket exclusive scan over NBLK block-counts (in place) + bucket total
__global__ __launch_bounds__(NBLK)
void bucket_scan1(int* __restrict__ hist_g, int* __restrict__ tot)
{
    __shared__ int sd[NBLK];
    int b = blockIdx.x, t = threadIdx.x;
    int v = hist_g[b * NBLK + t];
    sd[t] = v;
    __syncthreads();
    for (int off = 1; off < NBLK; off <<= 1) {
        int x = (t >= off) ? sd[t - off] : 0;
        __syncthreads();
        sd[t] += x;
        __syncthreads();
    }
    hist_g[b * NBLK + t] = sd[t] - v;   // exclusive
    if (t == NBLK - 1) tot[b] = sd[t];
}

// exclusive scan of bucket totals -> bkt_ptr[0..NB]
__global__ __launch_bounds__(1024)
void bucket_scan2(const int* __restrict__ tot, int* __restrict__ bkt_ptr, int NB, int E)
{
    __shared__ int sd[1024];
    int t = threadIdx.x;
    int v[4]; int s = 0;
#pragma unroll
    for (int j = 0; j < 4; ++j) {
        int idx = t * 4 + j;
        v[j] = (idx < NB) ? tot[idx] : 0;
        s += v[j];
    }
    sd[t] = s;
    __syncthreads();
    for (int off = 1; off < 1024; off <<= 1) {
        int x = (t >= off) ? sd[t - off] : 0;
        __syncthreads();
        sd[t] += x;
        __syncthreads();
    }
    int base = (t == 0) ? 0 : sd[t - 1];
#pragma unroll
    for (int j = 0; j < 4; ++j) {
        int idx = t * 4 + j;
        if (idx < NB) { bkt_ptr[idx] = base; base += v[j]; }
    }
    if (t == 0) bkt_ptr[NB] = E;
}

// grouped scatter: block s owns chunks [s*GRP, s*GRP+GRP) -> ~8 edges = 64B
// contiguous per bucket per block (full-line writes, no RFO amplification).
// Cursor init hist_g[b][s*GRP] is exact: the exclusive scan guarantees the
// group's edges occupy one contiguous destination range per bucket.
__global__ __launch_bounds__(SCT)
void bucket_scatter(const int* __restrict__ rows, const int* __restrict__ cols,
                    const float* __restrict__ vals, const int* __restrict__ bkt_ptr,
                    const int* __restrict__ hist_g, uint2* __restrict__ edges,
                    int E, int chunk, int NB)
{
    __shared__ int cur[NBMAX];
    int tid = threadIdx.x, blk = blockIdx.x;
    for (int b = tid; b < NB; b += SCT)
        cur[b] = bkt_ptr[b] + hist_g[b * NBLK + blk * GRP];
    __syncthreads();
    int s = blk * GRP * chunk, e = min(E, s + GRP * chunk);
    for (int i = s + tid; i < e; i += SCT) {
        int r = rows[i];
        int b = r >> SHIFT;
        uint2 ed;
        ed.x = (unsigned)cols[i] | ((unsigned)(r & 31) << 20);
        ed.y = __float_as_uint(vals[i]);
        int p = atomicAdd(&cur[b], 1);
        edges[p] = ed;
    }
}

// ------- SpMM + GEMM2 fused (R1's proven kernel): per-bucket in-LDS sort,
// register accum, MFMA epilogue. block = 256 thr = 4 waves; bucket = 32 rows;
// wave w accumulates rows [w*8, w*8+8), lane l = cols {2l, 2l+1}. Then temp
// tile -> LDS -> out[32x128] = prelu(T @ W16^T + bias), 16 MFMAs/wave.
__global__ __launch_bounds__(256, 8)
void spmm_fused(const int* __restrict__ bkt_ptr, const uint2* __restrict__ edges,
                const _Float16* __restrict__ h, const _Float16* __restrict__ W16,
                const float* __restrict__ bias, const float* __restrict__ alpha_p,
                float* __restrict__ out, int N)
{
    __shared__ uint2 eS[CAP];
    __shared__ _Float16 T[32 * LDK];
    __shared__ int bins[32], startS[33];

    const int tid  = threadIdx.x;
    const int wave = tid >> 6;
    const int lane = tid & 63;
    const int b    = blockIdx.x;
    const int s0   = bkt_ptr[b], e0 = bkt_ptr[b + 1];

    float acc[8][2] = {};

    for (int base = s0; base < e0; base += CAP) {
        const int n = min(CAP, e0 - base);
        if (tid < 32) bins[tid] = 0;
        __syncthreads();
        uint2 q[4];
#pragma unroll
        for (int u = 0; u < 4; ++u) {
            int i = tid + u * 256;
            if (i < n) {
                q[u] = edges[base + i];
                atomicAdd(&bins[q[u].x >> 20], 1);
            }
        }
        __syncthreads();
        if (tid < 32) {                    // wave-parallel 32-bin inclusive scan
            int x = bins[tid];
#pragma unroll
            for (int off = 1; off < 32; off <<= 1) {
                int y = __shfl_up(x, off);
                if (tid >= off) x += y;
            }
            startS[tid + 1] = x;
            if (tid == 0) startS[0] = 0;
            bins[tid] = x - bins[tid];     // bins becomes running cursor (exclusive)
        }
        __syncthreads();
#pragma unroll
        for (int u = 0; u < 4; ++u) {
            int i = tid + u * 256;
            if (i < n) {
                int p = atomicAdd(&bins[q[u].x >> 20], 1);
                eS[p] = q[u];
            }
        }
        __syncthreads();

#pragma unroll
        for (int j = 0; j < 8; ++j) {
            int r  = wave * 8 + j;
            int rs = startS[r], re = startS[r + 1];
            float a0r = acc[j][0], a1r = acc[j][1];
            int i = rs;
            for (; i + 7 < re; i += 8) {   // deep unroll: 8 gathers in flight
                uint2 q0 = eS[i],     q1 = eS[i + 1], q2 = eS[i + 2], q3 = eS[i + 3];
                uint2 q4 = eS[i + 4], q5 = eS[i + 5], q6 = eS[i + 6], q7 = eS[i + 7];
                half2v v0 = *(const half2v*)(h + (size_t)(q0.x & 0xFFFFF) * 128 + lane * 2);
                half2v v1 = *(const half2v*)(h + (size_t)(q1.x & 0xFFFFF) * 128 + lane * 2);
                half2v v2 = *(const half2v*)(h + (size_t)(q2.x & 0xFFFFF) * 128 + lane * 2);
                half2v v3 = *(const half2v*)(h + (size_t)(q3.x & 0xFFFFF) * 128 + lane * 2);
                half2v v4 = *(const half2v*)(h + (size_t)(q4.x & 0xFFFFF) * 128 + lane * 2);
                half2v v5 = *(const half2v*)(h + (size_t)(q5.x & 0xFFFFF) * 128 + lane * 2);
                half2v v6 = *(const half2v*)(h + (size_t)(q6.x & 0xFFFFF) * 128 + lane * 2);
                half2v v7 = *(const half2v*)(h + (size_t)(q7.x & 0xFFFFF) * 128 + lane * 2);
                float w0 = __uint_as_float(q0.y), w1 = __uint_as_float(q1.y);
                float w2 = __uint_as_float(q2.y), w3 = __uint_as_float(q3.y);
                float w4 = __uint_as_float(q4.y), w5 = __uint_as_float(q5.y);
                float w6 = __uint_as_float(q6.y), w7 = __uint_as_float(q7.y);
                a0r += w0 * (float)v0[0]; a1r += w0 * (float)v0[1];
                a0r += w1 * (float)v1[0]; a1r += w1 * (float)v1[1];
                a0r += w2 * (float)v2[0]; a1r += w2 * (float)v2[1];
                a0r += w3 * (float)v3[0]; a1r += w3 * (float)v3[1];
                a0r += w4 * (float)v4[0]; a1r += w4 * (float)v4[1];
                a0r += w5 * (float)v5[0]; a1r += w5 * (float)v5[1];
                a0r += w6 * (float)v6[0]; a1r += w6 * (float)v6[1];
                a0r += w7 * (float)v7[0]; a1r += w7 * (float)v7[1];
            }
            for (; i + 1 < re; i += 2) {
                uint2 q0 = eS[i], q1 = eS[i + 1];
                half2v v0 = *(const half2v*)(h + (size_t)(q0.x & 0xFFFFF) * 128 + lane * 2);
                half2v v1 = *(const half2v*)(h + (size_t)(q1.x & 0xFFFFF) * 128 + lane * 2);
                float w0 = __uint_as_float(q0.y), w1 = __uint_as_float(q1.y);
                a0r += w0 * (float)v0[0]; a1r += w0 * (float)v0[1];
                a0r += w1 * (float)v1[0]; a1r += w1 * (float)v1[1];
            }
            if (i < re) {
                uint2 q0 = eS[i];
                half2v v0 = *(const half2v*)(h + (size_t)(q0.x & 0xFFFFF) * 128 + lane * 2);
                float w0 = __uint_as_float(q0.y);
                a0r += w0 * (float)v0[0]; a1r += w0 * (float)v0[1];
            }
            acc[j][0] = a0r; acc[j][1] = a1r;
        }
        __syncthreads();   // protect eS before next chunk
    }

    // temp tile -> LDS (f16), row stride LDK breaks MFMA-read conflicts
#pragma unroll
    for (int j = 0; j < 8; ++j) {
        half2v o = { (_Float16)acc[j][0], (_Float16)acc[j][1] };
        *(half2v*)(&T[(wave * 8 + j) * LDK + lane * 2]) = o;
    }
    __syncthreads();

    // GEMM2 epilogue: out[32x128] = prelu(T @ W16^T + bias)
    const float alpha = *alpha_p;
    const int l15  = lane & 15;
    const int quad = lane >> 4;
    floatx4 c[2][2] = {};   // m-tiles {0,16} x n-tiles {wave*2, wave*2+1}
#pragma unroll
    for (int k0 = 0; k0 < 128; k0 += 32) {
        half8 a0 = *(const half8*)(&T[(     l15) * LDK + k0 + quad * 8]);
        half8 a1 = *(const half8*)(&T[(16 + l15) * LDK + k0 + quad * 8]);
#pragma unroll
        for (int nt = 0; nt < 2; ++nt) {
            int nrow = (wave * 2 + nt) * 16 + l15;
            half8 bf = *(const half8*)(W16 + nrow * 128 + k0 + quad * 8);
            c[0][nt] = __builtin_amdgcn_mfma_f32_16x16x32_f16(a0, bf, c[0][nt], 0, 0, 0);
            c[1][nt] = __builtin_amdgcn_mfma_f32_16x16x32_f16(a1, bf, c[1][nt], 0, 0, 0);
        }
    }
    const int row0 = b << SHIFT;
#pragma unroll
    for (int mt = 0; mt < 2; ++mt) {
#pragma unroll
        for (int nt = 0; nt < 2; ++nt) {
            int col = (wave * 2 + nt) * 16 + l15;
            float bcol = bias[col];
#pragma unroll
            for (int r = 0; r < 4; ++r) {
                int row = row0 + mt * 16 + quad * 4 + r;
                if (row < N) {
                    float v = c[mt][nt][r] + bcol;
                    v = (v >= 0.f) ? v : alpha * v;
                    out[(size_t)row * 128 + col] = v;
                }
            }
        }
    }
}

// ---------------- launcher ----------------
static inline size_t align256(size_t x) { return (x + 255) & ~(size_t)255; }

extern "C" void kernel_launch(void* const* d_in, const int* in_sizes, int n_in,
                              void* d_out, int out_size, void* d_ws, size_t ws_size,
                              hipStream_t stream)
{
    const float* AX        = (const float*)d_in[0];
    const int*   A_row     = (const int*)  d_in[1];
    const int*   A_col     = (const int*)  d_in[2];
    const float* A_val     = (const float*)d_in[3];
    const float* Wr_w      = (const float*)d_in[4];
    const float* Wr_b      = (const float*)d_in[5];
    const float* W_w       = (const float*)d_in[6];
    const float* W_b       = (const float*)d_in[7];
    const float* g_alpha   = (const float*)d_in[8];
    const float* act_alpha = (const float*)d_in[9];

    const int N = in_sizes[0] / 128;
    const int E = in_sizes[1];
    const int NB = (N + 31) >> SHIFT;            // 3125
    const int chunk = (E + NBLK - 1) / NBLK;     // 6250

    char* ws = (char*)d_ws;
    size_t off = 0;
    _Float16* h       = (_Float16*)(ws + off); off += align256((size_t)N * 128 * 2);
    uint2*    edges   = (uint2*)   (ws + off); off += align256((size_t)E * 8);
    int*      hist_g  = (int*)     (ws + off); off += align256((size_t)NB * NBLK * 4);
    int*      tot     = (int*)     (ws + off); off += align256((size_t)NB * 4);
    int*      bkt_ptr = (int*)     (ws + off); off += align256((size_t)(NB + 1) * 4);
    _Float16* W16     = (_Float16*)(ws + off); off += align256((size_t)128 * 128 * 2);
    (void)ws_size; (void)n_in; (void)out_size;

    const int gemmB = (N + 127) / 128;           // 782

    gemm_hist<<<NBLK + gemmB, 256, 0, stream>>>(AX, Wr_w, Wr_b, g_alpha, h, N,
                                                A_row, hist_g, E, chunk, NB,
                                                W_w, W16);
    bucket_scan1<<<NB, NBLK, 0, stream>>>(hist_g, tot);
    bucket_scan2<<<1, 1024, 0, stream>>>(tot, bkt_ptr, NB, E);
    bucket_scatter<<<SCTB, SCT, 0, stream>>>(A_row, A_col, A_val, bkt_ptr, hist_g,
                                             edges, E, chunk, NB);
    spmm_fused<<<NB, 256, 0, stream>>>(bkt_ptr, edges, h, W16, W_b, act_alpha,
                                       (float*)d_out, N);
}

// Round 8
// 266.735 us; speedup vs baseline: 1.2153x; 1.2153x over previous
//
#include <hip/hip_runtime.h>
#include <stdint.h>

// GCN layer: out = prelu(W @ segsum(A_val * h[A_col] -> A_row) + b, act_a)
//            h   = prelu(Wr @ AX + br, g_a)
// R6: GEMM2 fused into SpMM. R7: occ 61% @ 80.6us (best spmm). R8 FAILED:
// global atomic scatter 145us. R10 DECISIVE: beyond-L2 fetch pinned at
// 2.0-2.25 TB/s across 4 spmm structures -> random-line fetch CEILING;
// h-miss ~165MB == compulsory floor. spmm AT its roofline (~79us).
// R11 FAILED: threadfence last-block scan = 418us (device fence = XCD L2
// flush per block). R12: hist-in-GEMM fusion neutral. R13 FAILED: 64-block
// grouped scatter +37us (parallelism loss > write-allocate gain) -> scatter
// at 256 blocks is only ~15-25us; non-spmm time is SPREAD (gemm ~40-60,
// scatter ~20-40, scans ~20, gaps).
// R14: three separable cuts:
//  - scatter back to 256 blocks (R12-proven);
//  - GEMM drops Xs staging (zero cross-wave reuse): X fragments preloaded
//    into regs BEFORE the Ws barrier; LDS 69.6->34.8KB, 2->4 blocks/CU;
//  - scan2 dispatch killed: each scatter block inlines the tot[] scan in
//    LDS; block 0 writes bkt_ptr for spmm (next dispatch = safe ordering).
// 5 dispatches -> 4.

typedef _Float16 half8 __attribute__((ext_vector_type(8)));
typedef _Float16 half4 __attribute__((ext_vector_type(4)));
typedef _Float16 half2v __attribute__((ext_vector_type(2)));
typedef float floatx4 __attribute__((ext_vector_type(4)));

#define LDK 136        // GEMM LDS row stride in halfs: 128 + 8
#define SHIFT 5        // 32 rows per bucket
#define NBMAX 3200     // >= ceil(100000/32) = 3125
#define NBLK 256       // hist/scatter chunks
#define SCT 1024       // scatter threads per block
#define CAP 1024       // LDS edge capacity per sort chunk (max bucket ~650 expected)

// ------ fused GEMM1 + hist: blocks [0,NBLK) do the bucket histogram;
// ------ blocks [NBLK, NBLK+gemmB) do h = prelu(AX@Wr^T + br). No dependency.
// GEMM: Ws staged in LDS (4x cross-wave reuse); X read DIRECT to registers
// (no cross-wave reuse -> staging was pure overhead). LDS 34.8KB.
__global__ __launch_bounds__(256, 3)
void gemm_hist(const float* __restrict__ X, const float* __restrict__ Wr,
               const float* __restrict__ bias, const float* __restrict__ alpha_p,
               _Float16* __restrict__ out, int N,
               const int* __restrict__ rows, int* __restrict__ hist_g,
               int E, int chunk, int NB,
               const float* __restrict__ W, _Float16* __restrict__ W16)
{
    __shared__ _Float16 Ws[128 * LDK];
    const int tid = threadIdx.x;

    if (blockIdx.x < NBLK) {
        // ---------------- histogram path (layout: hist_g[b*NBLK + blk]) ----
        const int hb = blockIdx.x;
        int* lh = (int*)Ws;                       // alias LDS (12.8KB of 34.8KB)
        if (hb == 0) {
#pragma unroll
            for (int j = 0; j < 64; ++j)          // W fp32 -> f16 (16384 elems)
                W16[tid + j * 256] = (_Float16)W[tid + j * 256];
        }
        for (int i = tid; i < NB; i += 256) lh[i] = 0;
        __syncthreads();
        int s = hb * chunk, e = min(E, s + chunk);
        for (int i = s + tid; i < e; i += 256)
            atomicAdd(&lh[rows[i] >> SHIFT], 1);
        __syncthreads();
        for (int b = tid; b < NB; b += 256)
            hist_g[b * NBLK + hb] = lh[b];
        return;
    }

    // ---------------- GEMM path ----------------
    const int bm  = (blockIdx.x - NBLK) * 128;
    const float alpha = *alpha_p;
    const int wave = tid >> 6;
    const int lane = tid & 63;
    const int l15  = lane & 15;
    const int quad = lane >> 4;

    // preload X fragments to registers (overlaps Ws staging + barrier)
    half8 a[2][4];
#pragma unroll
    for (int mt = 0; mt < 2; ++mt) {
        const int xrow = bm + wave * 32 + mt * 16 + l15;
        const float* xp = X + (size_t)xrow * 128 + quad * 8;
        const bool ok = xrow < N;
#pragma unroll
        for (int k = 0; k < 4; ++k) {
            half8 hv = {};
            if (ok) {
                float4 f0 = *(const float4*)(xp + k * 32);
                float4 f1 = *(const float4*)(xp + k * 32 + 4);
                hv[0] = (_Float16)f0.x; hv[1] = (_Float16)f0.y;
                hv[2] = (_Float16)f0.z; hv[3] = (_Float16)f0.w;
                hv[4] = (_Float16)f1.x; hv[5] = (_Float16)f1.y;
                hv[6] = (_Float16)f1.z; hv[7] = (_Float16)f1.w;
            }
            a[mt][k] = hv;
        }
    }

#pragma unroll
    for (int i = 0; i < 16; ++i) {
        int c   = tid + i * 256;
        int row = c >> 5;
        int coff = (c & 31) * 4;
        float4 f = *(const float4*)(Wr + row * 128 + coff);
        half4 hv = { (_Float16)f.x, (_Float16)f.y, (_Float16)f.z, (_Float16)f.w };
        *(half4*)(&Ws[row * LDK + coff]) = hv;
    }
    __syncthreads();

    floatx4 acc[2][8] = {};
#pragma unroll
    for (int k = 0; k < 4; ++k) {
        const int k0 = k * 32;
        half8 b[8];
#pragma unroll
        for (int n = 0; n < 8; ++n)
            b[n] = *(const half8*)(&Ws[(n * 16 + l15) * LDK + k0 + quad * 8]);
#pragma unroll
        for (int n = 0; n < 8; ++n) {
            acc[0][n] = __builtin_amdgcn_mfma_f32_16x16x32_f16(a[0][k], b[n], acc[0][n], 0, 0, 0);
            acc[1][n] = __builtin_amdgcn_mfma_f32_16x16x32_f16(a[1][k], b[n], acc[1][n], 0, 0, 0);
        }
    }

#pragma unroll
    for (int mt = 0; mt < 2; ++mt) {
#pragma unroll
        for (int n = 0; n < 8; ++n) {
#pragma unroll
            for (int r = 0; r < 4; ++r) {
                int row = bm + wave * 32 + mt * 16 + quad * 4 + r;
                int col = n * 16 + l15;
                if (row < N) {
                    float v = acc[mt][n][r] + bias[col];
                    v = (v >= 0.f) ? v : alpha * v;
                    out[(size_t)row * 128 + col] = (_Float16)v;
                }
            }
        }
    }
}

// per-bucket exclusive scan over NBLK block-counts (in place) + bucket total
__global__ __launch_bounds__(NBLK)
void bucket_scan1(int* __restrict__ hist_g, int* __restrict__ tot)
{
    __shared__ int sd[NBLK];
    int b = blockIdx.x, t = threadIdx.x;
    int v = hist_g[b * NBLK + t];
    sd[t] = v;
    __syncthreads();
    for (int off = 1; off < NBLK; off <<= 1) {
        int x = (t >= off) ? sd[t - off] : 0;
        __syncthreads();
        sd[t] += x;
        __syncthreads();
    }
    hist_g[b * NBLK + t] = sd[t] - v;   // exclusive
    if (t == NBLK - 1) tot[b] = sd[t];
}

// scatter with INLINED bucket-total scan: every block computes the exclusive
// scan of tot[] in LDS (parallel, L2-hot, ~5us); block 0 also publishes
// bkt_ptr for spmm (consumed next dispatch -> ordering via boundary, no fence).
__global__ __launch_bounds__(SCT)
void bucket_scatter(const int* __restrict__ rows, const int* __restrict__ cols,
                    const float* __restrict__ vals, const int* __restrict__ tot,
                    const int* __restrict__ hist_g, uint2* __restrict__ edges,
                    int* __restrict__ bkt_ptr, int E, int chunk, int NB)
{
    __shared__ int sd[SCT];
    __shared__ int cur[NBMAX];
    const int t = threadIdx.x, blk = blockIdx.x;

    int v[4]; int s = 0;
#pragma unroll
    for (int j = 0; j < 4; ++j) {
        int idx = t * 4 + j;
        v[j] = (idx < NB) ? tot[idx] : 0;
        s += v[j];
    }
    sd[t] = s;
    __syncthreads();
    for (int off = 1; off < SCT; off <<= 1) {
        int x = (t >= off) ? sd[t - off] : 0;
        __syncthreads();
        sd[t] += x;
        __syncthreads();
    }
    int base = (t == 0) ? 0 : sd[t - 1];
#pragma unroll
    for (int j = 0; j < 4; ++j) {
        int idx = t * 4 + j;
        if (idx < NB) {
            cur[idx] = base + hist_g[idx * NBLK + blk];
            if (blk == 0) bkt_ptr[idx] = base;
            base += v[j];
        }
    }
    if (blk == 0 && t == 0) bkt_ptr[NB] = E;
    __syncthreads();

    int s0 = blk * chunk, e0 = min(E, s0 + chunk);
    for (int i = s0 + t; i < e0; i += SCT) {
        int r = rows[i];
        int b = r >> SHIFT;
        uint2 ed;
        ed.x = (unsigned)cols[i] | ((unsigned)(r & 31) << 20);
        ed.y = __float_as_uint(vals[i]);
        int p = atomicAdd(&cur[b], 1);
        edges[p] = ed;
    }
}

// ------- SpMM + GEMM2 fused (R1's proven kernel): per-bucket in-LDS sort,
// register accum, MFMA epilogue. block = 256 thr = 4 waves; bucket = 32 rows;
// wave w accumulates rows [w*8, w*8+8), lane l = cols {2l, 2l+1}. Then temp
// tile -> LDS -> out[32x128] = prelu(T @ W16^T + bias), 16 MFMAs/wave.
__global__ __launch_bounds__(256, 8)
void spmm_fused(const int* __restrict__ bkt_ptr, const uint2* __restrict__ edges,
                const _Float16* __restrict__ h, const _Float16* __restrict__ W16,
                const float* __restrict__ bias, const float* __restrict__ alpha_p,
                float* __restrict__ out, int N)
{
    __shared__ uint2 eS[CAP];
    __shared__ _Float16 T[32 * LDK];
    __shared__ int bins[32], startS[33];

    const int tid  = threadIdx.x;
    const int wave = tid >> 6;
    const int lane = tid & 63;
    const int b    = blockIdx.x;
    const int s0   = bkt_ptr[b], e0 = bkt_ptr[b + 1];

    float acc[8][2] = {};

    for (int base = s0; base < e0; base += CAP) {
        const int n = min(CAP, e0 - base);
        if (tid < 32) bins[tid] = 0;
        __syncthreads();
        uint2 q[4];
#pragma unroll
        for (int u = 0; u < 4; ++u) {
            int i = tid + u * 256;
            if (i < n) {
                q[u] = edges[base + i];
                atomicAdd(&bins[q[u].x >> 20], 1);
            }
        }
        __syncthreads();
        if (tid < 32) {                    // wave-parallel 32-bin inclusive scan
            int x = bins[tid];
#pragma unroll
            for (int off = 1; off < 32; off <<= 1) {
                int y = __shfl_up(x, off);
                if (tid >= off) x += y;
            }
            startS[tid + 1] = x;
            if (tid == 0) startS[0] = 0;
            bins[tid] = x - bins[tid];     // bins becomes running cursor (exclusive)
        }
        __syncthreads();
#pragma unroll
        for (int u = 0; u < 4; ++u) {
            int i = tid + u * 256;
            if (i < n) {
                int p = atomicAdd(&bins[q[u].x >> 20], 1);
                eS[p] = q[u];
            }
        }
        __syncthreads();

#pragma unroll
        for (int j = 0; j < 8; ++j) {
            int r  = wave * 8 + j;
            int rs = startS[r], re = startS[r + 1];
            float a0r = acc[j][0], a1r = acc[j][1];
            int i = rs;
            for (; i + 7 < re; i += 8) {   // deep unroll: 8 gathers in flight
                uint2 q0 = eS[i],     q1 = eS[i + 1], q2 = eS[i + 2], q3 = eS[i + 3];
                uint2 q4 = eS[i + 4], q5 = eS[i + 5], q6 = eS[i + 6], q7 = eS[i + 7];
                half2v v0 = *(const half2v*)(h + (size_t)(q0.x & 0xFFFFF) * 128 + lane * 2);
                half2v v1 = *(const half2v*)(h + (size_t)(q1.x & 0xFFFFF) * 128 + lane * 2);
                half2v v2 = *(const half2v*)(h + (size_t)(q2.x & 0xFFFFF) * 128 + lane * 2);
                half2v v3 = *(const half2v*)(h + (size_t)(q3.x & 0xFFFFF) * 128 + lane * 2);
                half2v v4 = *(const half2v*)(h + (size_t)(q4.x & 0xFFFFF) * 128 + lane * 2);
                half2v v5 = *(const half2v*)(h + (size_t)(q5.x & 0xFFFFF) * 128 + lane * 2);
                half2v v6 = *(const half2v*)(h + (size_t)(q6.x & 0xFFFFF) * 128 + lane * 2);
                half2v v7 = *(const half2v*)(h + (size_t)(q7.x & 0xFFFFF) * 128 + lane * 2);
                float w0 = __uint_as_float(q0.y), w1 = __uint_as_float(q1.y);
                float w2 = __uint_as_float(q2.y), w3 = __uint_as_float(q3.y);
                float w4 = __uint_as_float(q4.y), w5 = __uint_as_float(q5.y);
                float w6 = __uint_as_float(q6.y), w7 = __uint_as_float(q7.y);
                a0r += w0 * (float)v0[0]; a1r += w0 * (float)v0[1];
                a0r += w1 * (float)v1[0]; a1r += w1 * (float)v1[1];
                a0r += w2 * (float)v2[0]; a1r += w2 * (float)v2[1];
                a0r += w3 * (float)v3[0]; a1r += w3 * (float)v3[1];
                a0r += w4 * (float)v4[0]; a1r += w4 * (float)v4[1];
                a0r += w5 * (float)v5[0]; a1r += w5 * (float)v5[1];
                a0r += w6 * (float)v6[0]; a1r += w6 * (float)v6[1];
                a0r += w7 * (float)v7[0]; a1r += w7 * (float)v7[1];
            }
            for (; i + 1 < re; i += 2) {
                uint2 q0 = eS[i], q1 = eS[i + 1];
                half2v v0 = *(const half2v*)(h + (size_t)(q0.x & 0xFFFFF) * 128 + lane * 2);
                half2v v1 = *(const half2v*)(h + (size_t)(q1.x & 0xFFFFF) * 128 + lane * 2);
                float w0 = __uint_as_float(q0.y), w1 = __uint_as_float(q1.y);
                a0r += w0 * (float)v0[0]; a1r += w0 * (float)v0[1];
                a0r += w1 * (float)v1[0]; a1r += w1 * (float)v1[1];
            }
            if (i < re) {
                uint2 q0 = eS[i];
                half2v v0 = *(const half2v*)(h + (size_t)(q0.x & 0xFFFFF) * 128 + lane * 2);
                float w0 = __uint_as_float(q0.y);
                a0r += w0 * (float)v0[0]; a1r += w0 * (float)v0[1];
            }
            acc[j][0] = a0r; acc[j][1] = a1r;
        }
        __syncthreads();   // protect eS before next chunk
    }

    // temp tile -> LDS (f16), row stride LDK breaks MFMA-read conflicts
#pragma unroll
    for (int j = 0; j < 8; ++j) {
        half2v o = { (_Float16)acc[j][0], (_Float16)acc[j][1] };
        *(half2v*)(&T[(wave * 8 + j) * LDK + lane * 2]) = o;
    }
    __syncthreads();

    // GEMM2 epilogue: out[32x128] = prelu(T @ W16^T + bias)
    const float alpha = *alpha_p;
    const int l15  = lane & 15;
    const int quad = lane >> 4;
    floatx4 c[2][2] = {};   // m-tiles {0,16} x n-tiles {wave*2, wave*2+1}
#pragma unroll
    for (int k0 = 0; k0 < 128; k0 += 32) {
        half8 a0 = *(const half8*)(&T[(     l15) * LDK + k0 + quad * 8]);
        half8 a1 = *(const half8*)(&T[(16 + l15) * LDK + k0 + quad * 8]);
#pragma unroll
        for (int nt = 0; nt < 2; ++nt) {
            int nrow = (wave * 2 + nt) * 16 + l15;
            half8 bf = *(const half8*)(W16 + nrow * 128 + k0 + quad * 8);
            c[0][nt] = __builtin_amdgcn_mfma_f32_16x16x32_f16(a0, bf, c[0][nt], 0, 0, 0);
            c[1][nt] = __builtin_amdgcn_mfma_f32_16x16x32_f16(a1, bf, c[1][nt], 0, 0, 0);
        }
    }
    const int row0 = b << SHIFT;
#pragma unroll
    for (int mt = 0; mt < 2; ++mt) {
#pragma unroll
        for (int nt = 0; nt < 2; ++nt) {
            int col = (wave * 2 + nt) * 16 + l15;
            float bcol = bias[col];
#pragma unroll
            for (int r = 0; r < 4; ++r) {
                int row = row0 + mt * 16 + quad * 4 + r;
                if (row < N) {
                    float v = c[mt][nt][r] + bcol;
                    v = (v >= 0.f) ? v : alpha * v;
                    out[(size_t)row * 128 + col] = v;
                }
            }
        }
    }
}

// ---------------- launcher ----------------
static inline size_t align256(size_t x) { return (x + 255) & ~(size_t)255; }

extern "C" void kernel_launch(void* const* d_in, const int* in_sizes, int n_in,
                              void* d_out, int out_size, void* d_ws, size_t ws_size,
                              hipStream_t stream)
{
    const float* AX        = (const float*)d_in[0];
    const int*   A_row     = (const int*)  d_in[1];
    const int*   A_col     = (const int*)  d_in[2];
    const float* A_val     = (const float*)d_in[3];
    const float* Wr_w      = (const float*)d_in[4];
    const float* Wr_b      = (const float*)d_in[5];
    const float* W_w       = (const float*)d_in[6];
    const float* W_b       = (const float*)d_in[7];
    const float* g_alpha   = (const float*)d_in[8];
    const float* act_alpha = (const float*)d_in[9];

    const int N = in_sizes[0] / 128;
    const int E = in_sizes[1];
    const int NB = (N + 31) >> SHIFT;            // 3125
    const int chunk = (E + NBLK - 1) / NBLK;     // 6250

    char* ws = (char*)d_ws;
    size_t off = 0;
    _Float16* h       = (_Float16*)(ws + off); off += align256((size_t)N * 128 * 2);
    uint2*    edges   = (uint2*)   (ws + off); off += align256((size_t)E * 8);
    int*      hist_g  = (int*)     (ws + off); off += align256((size_t)NB * NBLK * 4);
    int*      tot     = (int*)     (ws + off); off += align256((size_t)NB * 4);
    int*      bkt_ptr = (int*)     (ws + off); off += align256((size_t)(NB + 1) * 4);
    _Float16* W16     = (_Float16*)(ws + off); off += align256((size_t)128 * 128 * 2);
    (void)ws_size; (void)n_in; (void)out_size;

    const int gemmB = (N + 127) / 128;           // 782

    gemm_hist<<<NBLK + gemmB, 256, 0, stream>>>(AX, Wr_w, Wr_b, g_alpha, h, N,
                                                A_row, hist_g, E, chunk, NB,
                                                W_w, W16);
    bucket_scan1<<<NB, NBLK, 0, stream>>>(hist_g, tot);
    bucket_scatter<<<NBLK, SCT, 0, stream>>>(A_row, A_col, A_val, tot, hist_g,
                                             edges, bkt_ptr, E, chunk, NB);
    spmm_fused<<<NB, 256, 0, stream>>>(bkt_ptr, edges, h, W16, W_b, act_alpha,
                                       (float*)d_out, N);
}

// Round 9
// 250.236 us; speedup vs baseline: 1.2954x; 1.0659x over previous
//
#include <hip/hip_runtime.h>
#include <stdint.h>

// GCN layer: out = prelu(W @ segsum(A_val * h[A_col] -> A_row) + b, act_a)
//            h   = prelu(Wr @ AX + br, g_a)
// spmm (R1/R7 kernel) is AT its random-line fetch ceiling: ~80us, beyond-L2
// fetch pinned 2.0-2.25 TB/s across 4 structures (R10); h-miss ~165MB ==
// compulsory floor (8 XCDs x 86% col coverage x 25.6MB). Failures logged:
// R8 global-atomic scatter (contention+write-allocate), R11 threadfence
// last-block scan (device fence = XCD L2 flush per block), R13 64-block
// scatter (parallelism loss > line-grouping gain).
// R14 WIN (266.7): X-staging dropped from GEMM (no cross-wave reuse),
// scan2 inlined into scatter, 4 dispatches.
// R15: overlap GEMM with the EXPENSIVE stage + cheap scan:
//  - hist standalone (exposes ~13us) but GEMM now rides the SCATTER
//    dispatch (the ~40-55us stage) as 16-wave/1024-thr blocks: wave w
//    owns (m-tile w>>1, n-half w&1); a[4]/acc[4] -> ~55 VGPR fits.
//  - scan1_fast: wave-per-bucket, shfl-only (no barriers, no LDS),
//    782 blocks; replaces 16-barrier log-scan x 3125 blocks.
// Pipeline: hist -> scan1_fast -> (scatter || gemm) -> spmm.

typedef _Float16 half8 __attribute__((ext_vector_type(8)));
typedef _Float16 half4 __attribute__((ext_vector_type(4)));
typedef _Float16 half2v __attribute__((ext_vector_type(2)));
typedef float floatx4 __attribute__((ext_vector_type(4)));

#define LDK 136        // GEMM LDS row stride in halfs: 128 + 8
#define SHIFT 5        // 32 rows per bucket
#define NBMAX 3200     // >= ceil(100000/32) = 3125
#define NBLK 256       // hist/scatter chunks
#define SCT 1024       // hist/scatter threads per block
#define CAP 1024       // LDS edge capacity per sort chunk (max bucket ~650 expected)

// ---------------- hist: per-chunk bucket histogram (R1-proven shape) -------
// Block 0 also converts W fp32 -> f16 (consumed 2 dispatches later).
__global__ __launch_bounds__(SCT)
void bucket_hist(const int* __restrict__ rows, int* __restrict__ hist_g,
                 int E, int chunk, int NB,
                 const float* __restrict__ W, _Float16* __restrict__ W16)
{
    __shared__ int lh[NBMAX];
    int tid = threadIdx.x, blk = blockIdx.x;
    if (blk == 0) {
#pragma unroll
        for (int j = 0; j < 16; ++j) W16[tid + j * 1024] = (_Float16)W[tid + j * 1024];
    }
    for (int i = tid; i < NB; i += SCT) lh[i] = 0;
    __syncthreads();
    int s = blk * chunk, e = min(E, s + chunk);
    for (int i = s + tid; i < e; i += SCT)
        atomicAdd(&lh[rows[i] >> SHIFT], 1);
    __syncthreads();
    for (int b = tid; b < NB; b += SCT)
        hist_g[b * NBLK + blk] = lh[b];
}

// ---------------- scan1_fast: wave-per-bucket, shfl-only -------------------
// Wave w of block blk scans bucket b = blk*4 + w: 256 counts, 4/lane
// (contiguous 16B), lane-serial sum + wave-inclusive shfl scan. No barriers.
__global__ __launch_bounds__(256)
void scan1_fast(int* __restrict__ hist_g, int* __restrict__ tot, int NB)
{
    const int wave = threadIdx.x >> 6;
    const int lane = threadIdx.x & 63;
    const int b = blockIdx.x * 4 + wave;
    if (b >= NB) return;

    int* p = hist_g + b * NBLK + lane * 4;
    int v0 = p[0], v1 = p[1], v2 = p[2], v3 = p[3];
    int s = v0 + v1 + v2 + v3;

    int x = s;
#pragma unroll
    for (int off = 1; off < 64; off <<= 1) {
        int y = __shfl_up(x, off);
        if (lane >= off) x += y;
    }
    int run = x - s;                 // exclusive base for this lane
    p[0] = run; run += v0;
    p[1] = run; run += v1;
    p[2] = run; run += v2;
    p[3] = run;
    if (lane == 63) tot[b] = x;      // bucket total
}

// ------ fused scatter + GEMM1 (1024-thr blocks) ----------------------------
// blocks [0,NBLK): scatter with inlined tot-scan (R14-proven). blocks
// [NBLK,NBLK+gemmB): h = prelu(AX@Wr^T+br), 16 waves/block, one 128-row
// tile; wave w owns (m-tile w>>1, n-half w&1); Ws staged once per block;
// X read direct to regs (no cross-wave reuse).
__global__ __launch_bounds__(1024, 4)
void scatter_gemm(const int* __restrict__ rows, const int* __restrict__ cols,
                  const float* __restrict__ vals, const int* __restrict__ tot,
                  const int* __restrict__ hist_g, uint2* __restrict__ edges,
                  int* __restrict__ bkt_ptr, int E, int chunk, int NB,
                  const float* __restrict__ X, const float* __restrict__ Wr,
                  const float* __restrict__ bias, const float* __restrict__ alpha_p,
                  _Float16* __restrict__ out, int N)
{
    __shared__ _Float16 Ws[128 * LDK];   // 34.8KB; scatter aliases a prefix
    const int tid = threadIdx.x;

    if (blockIdx.x < NBLK) {
        // ---------------- scatter path ----------------
        int* sd  = (int*)Ws;                     // [SCT]      4KB
        int* cur = (int*)Ws + SCT;               // [NBMAX]   12.8KB
        const int blk = blockIdx.x;

        int v[4]; int s = 0;
#pragma unroll
        for (int j = 0; j < 4; ++j) {
            int idx = tid * 4 + j;
            v[j] = (idx < NB) ? tot[idx] : 0;
            s += v[j];
        }
        sd[tid] = s;
        __syncthreads();
        for (int off = 1; off < SCT; off <<= 1) {
            int x = (tid >= off) ? sd[tid - off] : 0;
            __syncthreads();
            sd[tid] += x;
            __syncthreads();
        }
        int base = (tid == 0) ? 0 : sd[tid - 1];
#pragma unroll
        for (int j = 0; j < 4; ++j) {
            int idx = tid * 4 + j;
            if (idx < NB) {
                cur[idx] = base + hist_g[idx * NBLK + blk];
                if (blk == 0) bkt_ptr[idx] = base;
                base += v[j];
            }
        }
        if (blk == 0 && tid == 0) bkt_ptr[NB] = E;
        __syncthreads();

        int s0 = blk * chunk, e0 = min(E, s0 + chunk);
        for (int i = s0 + tid; i < e0; i += SCT) {
            int r = rows[i];
            int b = r >> SHIFT;
            uint2 ed;
            ed.x = (unsigned)cols[i] | ((unsigned)(r & 31) << 20);
            ed.y = __float_as_uint(vals[i]);
            int p = atomicAdd(&cur[b], 1);
            edges[p] = ed;
        }
        return;
    }

    // ---------------- GEMM path ----------------
    const int bm  = (blockIdx.x - NBLK) * 128;
    const float alpha = *alpha_p;
    const int wave = tid >> 6;       // 0..15
    const int lane = tid & 63;
    const int l15  = lane & 15;
    const int quad = lane >> 4;
    const int mt   = wave >> 1;      // m-tile 0..7 (16 rows each)
    const int nh   = wave & 1;       // n-half 0..1 (64 cols each)

    // preload X frags for this wave's m-tile (overlaps Ws staging + barrier)
    half8 a[4];
    {
        const int xrow = bm + mt * 16 + l15;
        const bool ok = xrow < N;
        const float* xp = X + (size_t)xrow * 128 + quad * 8;
#pragma unroll
        for (int k = 0; k < 4; ++k) {
            half8 hv = {};
            if (ok) {
                float4 f0 = *(const float4*)(xp + k * 32);
                float4 f1 = *(const float4*)(xp + k * 32 + 4);
                hv[0] = (_Float16)f0.x; hv[1] = (_Float16)f0.y;
                hv[2] = (_Float16)f0.z; hv[3] = (_Float16)f0.w;
                hv[4] = (_Float16)f1.x; hv[5] = (_Float16)f1.y;
                hv[6] = (_Float16)f1.z; hv[7] = (_Float16)f1.w;
            }
            a[k] = hv;
        }
    }

#pragma unroll
    for (int i = 0; i < 4; ++i) {    // stage W (4x cross-wave reuse), 1024 thr
        int c   = tid + i * 1024;
        int row = c >> 5;
        int coff = (c & 31) * 4;
        float4 f = *(const float4*)(Wr + row * 128 + coff);
        half4 hv = { (_Float16)f.x, (_Float16)f.y, (_Float16)f.z, (_Float16)f.w };
        *(half4*)(&Ws[row * LDK + coff]) = hv;
    }
    __syncthreads();

    floatx4 acc[4] = {};
#pragma unroll
    for (int k = 0; k < 4; ++k) {
#pragma unroll
        for (int n = 0; n < 4; ++n) {
            int nc = nh * 4 + n;
            half8 b = *(const half8*)(&Ws[(nc * 16 + l15) * LDK + k * 32 + quad * 8]);
            acc[n] = __builtin_amdgcn_mfma_f32_16x16x32_f16(a[k], b, acc[n], 0, 0, 0);
        }
    }

#pragma unroll
    for (int n = 0; n < 4; ++n) {
        int col = (nh * 4 + n) * 16 + l15;
        float bcol = bias[col];
#pragma unroll
        for (int r = 0; r < 4; ++r) {
            int row = bm + mt * 16 + quad * 4 + r;
            if (row < N) {
                float v = acc[n][r] + bcol;
                v = (v >= 0.f) ? v : alpha * v;
                out[(size_t)row * 128 + col] = (_Float16)v;
            }
        }
    }
}

// ------- SpMM + GEMM2 fused (R1's proven kernel): per-bucket in-LDS sort,
// register accum, MFMA epilogue. block = 256 thr = 4 waves; bucket = 32 rows;
// wave w accumulates rows [w*8, w*8+8), lane l = cols {2l, 2l+1}. Then temp
// tile -> LDS -> out[32x128] = prelu(T @ W16^T + bias), 16 MFMAs/wave.
__global__ __launch_bounds__(256, 8)
void spmm_fused(const int* __restrict__ bkt_ptr, const uint2* __restrict__ edges,
                const _Float16* __restrict__ h, const _Float16* __restrict__ W16,
                const float* __restrict__ bias, const float* __restrict__ alpha_p,
                float* __restrict__ out, int N)
{
    __shared__ uint2 eS[CAP];
    __shared__ _Float16 T[32 * LDK];
    __shared__ int bins[32], startS[33];

    const int tid  = threadIdx.x;
    const int wave = tid >> 6;
    const int lane = tid & 63;
    const int b    = blockIdx.x;
    const int s0   = bkt_ptr[b], e0 = bkt_ptr[b + 1];

    float acc[8][2] = {};

    for (int base = s0; base < e0; base += CAP) {
        const int n = min(CAP, e0 - base);
        if (tid < 32) bins[tid] = 0;
        __syncthreads();
        uint2 q[4];
#pragma unroll
        for (int u = 0; u < 4; ++u) {
            int i = tid + u * 256;
            if (i < n) {
                q[u] = edges[base + i];
                atomicAdd(&bins[q[u].x >> 20], 1);
            }
        }
        __syncthreads();
        if (tid < 32) {                    // wave-parallel 32-bin inclusive scan
            int x = bins[tid];
#pragma unroll
            for (int off = 1; off < 32; off <<= 1) {
                int y = __shfl_up(x, off);
                if (tid >= off) x += y;
            }
            startS[tid + 1] = x;
            if (tid == 0) startS[0] = 0;
            bins[tid] = x - bins[tid];     // bins becomes running cursor (exclusive)
        }
        __syncthreads();
#pragma unroll
        for (int u = 0; u < 4; ++u) {
            int i = tid + u * 256;
            if (i < n) {
                int p = atomicAdd(&bins[q[u].x >> 20], 1);
                eS[p] = q[u];
            }
        }
        __syncthreads();

#pragma unroll
        for (int j = 0; j < 8; ++j) {
            int r  = wave * 8 + j;
            int rs = startS[r], re = startS[r + 1];
            float a0r = acc[j][0], a1r = acc[j][1];
            int i = rs;
            for (; i + 7 < re; i += 8) {   // deep unroll: 8 gathers in flight
                uint2 q0 = eS[i],     q1 = eS[i + 1], q2 = eS[i + 2], q3 = eS[i + 3];
                uint2 q4 = eS[i + 4], q5 = eS[i + 5], q6 = eS[i + 6], q7 = eS[i + 7];
                half2v v0 = *(const half2v*)(h + (size_t)(q0.x & 0xFFFFF) * 128 + lane * 2);
                half2v v1 = *(const half2v*)(h + (size_t)(q1.x & 0xFFFFF) * 128 + lane * 2);
                half2v v2 = *(const half2v*)(h + (size_t)(q2.x & 0xFFFFF) * 128 + lane * 2);
                half2v v3 = *(const half2v*)(h + (size_t)(q3.x & 0xFFFFF) * 128 + lane * 2);
                half2v v4 = *(const half2v*)(h + (size_t)(q4.x & 0xFFFFF) * 128 + lane * 2);
                half2v v5 = *(const half2v*)(h + (size_t)(q5.x & 0xFFFFF) * 128 + lane * 2);
                half2v v6 = *(const half2v*)(h + (size_t)(q6.x & 0xFFFFF) * 128 + lane * 2);
                half2v v7 = *(const half2v*)(h + (size_t)(q7.x & 0xFFFFF) * 128 + lane * 2);
                float w0 = __uint_as_float(q0.y), w1 = __uint_as_float(q1.y);
                float w2 = __uint_as_float(q2.y), w3 = __uint_as_float(q3.y);
                float w4 = __uint_as_float(q4.y), w5 = __uint_as_float(q5.y);
                float w6 = __uint_as_float(q6.y), w7 = __uint_as_float(q7.y);
                a0r += w0 * (float)v0[0]; a1r += w0 * (float)v0[1];
                a0r += w1 * (float)v1[0]; a1r += w1 * (float)v1[1];
                a0r += w2 * (float)v2[0]; a1r += w2 * (float)v2[1];
                a0r += w3 * (float)v3[0]; a1r += w3 * (float)v3[1];
                a0r += w4 * (float)v4[0]; a1r += w4 * (float)v4[1];
                a0r += w5 * (float)v5[0]; a1r += w5 * (float)v5[1];
                a0r += w6 * (float)v6[0]; a1r += w6 * (float)v6[1];
                a0r += w7 * (float)v7[0]; a1r += w7 * (float)v7[1];
            }
            for (; i + 1 < re; i += 2) {
                uint2 q0 = eS[i], q1 = eS[i + 1];
                half2v v0 = *(const half2v*)(h + (size_t)(q0.x & 0xFFFFF) * 128 + lane * 2);
                half2v v1 = *(const half2v*)(h + (size_t)(q1.x & 0xFFFFF) * 128 + lane * 2);
                float w0 = __uint_as_float(q0.y), w1 = __uint_as_float(q1.y);
                a0r += w0 * (float)v0[0]; a1r += w0 * (float)v0[1];
                a0r += w1 * (float)v1[0]; a1r += w1 * (float)v1[1];
            }
            if (i < re) {
                uint2 q0 = eS[i];
                half2v v0 = *(const half2v*)(h + (size_t)(q0.x & 0xFFFFF) * 128 + lane * 2);
                float w0 = __uint_as_float(q0.y);
                a0r += w0 * (float)v0[0]; a1r += w0 * (float)v0[1];
            }
            acc[j][0] = a0r; acc[j][1] = a1r;
        }
        __syncthreads();   // protect eS before next chunk
    }

    // temp tile -> LDS (f16), row stride LDK breaks MFMA-read conflicts
#pragma unroll
    for (int j = 0; j < 8; ++j) {
        half2v o = { (_Float16)acc[j][0], (_Float16)acc[j][1] };
        *(half2v*)(&T[(wave * 8 + j) * LDK + lane * 2]) = o;
    }
    __syncthreads();

    // GEMM2 epilogue: out[32x128] = prelu(T @ W16^T + bias)
    const float alpha = *alpha_p;
    const int l15  = lane & 15;
    const int quad = lane >> 4;
    floatx4 c[2][2] = {};   // m-tiles {0,16} x n-tiles {wave*2, wave*2+1}
#pragma unroll
    for (int k0 = 0; k0 < 128; k0 += 32) {
        half8 a0 = *(const half8*)(&T[(     l15) * LDK + k0 + quad * 8]);
        half8 a1 = *(const half8*)(&T[(16 + l15) * LDK + k0 + quad * 8]);
#pragma unroll
        for (int nt = 0; nt < 2; ++nt) {
            int nrow = (wave * 2 + nt) * 16 + l15;
            half8 bf = *(const half8*)(W16 + nrow * 128 + k0 + quad * 8);
            c[0][nt] = __builtin_amdgcn_mfma_f32_16x16x32_f16(a0, bf, c[0][nt], 0, 0, 0);
            c[1][nt] = __builtin_amdgcn_mfma_f32_16x16x32_f16(a1, bf, c[1][nt], 0, 0, 0);
        }
    }
    const int row0 = b << SHIFT;
#pragma unroll
    for (int mt = 0; mt < 2; ++mt) {
#pragma unroll
        for (int nt = 0; nt < 2; ++nt) {
            int col = (wave * 2 + nt) * 16 + l15;
            float bcol = bias[col];
#pragma unroll
            for (int r = 0; r < 4; ++r) {
                int row = row0 + mt * 16 + quad * 4 + r;
                if (row < N) {
                    float v = c[mt][nt][r] + bcol;
                    v = (v >= 0.f) ? v : alpha * v;
                    out[(size_t)row * 128 + col] = v;
                }
            }
        }
    }
}

// ---------------- launcher ----------------
static inline size_t align256(size_t x) { return (x + 255) & ~(size_t)255; }

extern "C" void kernel_launch(void* const* d_in, const int* in_sizes, int n_in,
                              void* d_out, int out_size, void* d_ws, size_t ws_size,
                              hipStream_t stream)
{
    const float* AX        = (const float*)d_in[0];
    const int*   A_row     = (const int*)  d_in[1];
    const int*   A_col     = (const int*)  d_in[2];
    const float* A_val     = (const float*)d_in[3];
    const float* Wr_w      = (const float*)d_in[4];
    const float* Wr_b      = (const float*)d_in[5];
    const float* W_w       = (const float*)d_in[6];
    const float* W_b       = (const float*)d_in[7];
    const float* g_alpha   = (const float*)d_in[8];
    const float* act_alpha = (const float*)d_in[9];

    const int N = in_sizes[0] / 128;
    const int E = in_sizes[1];
    const int NB = (N + 31) >> SHIFT;            // 3125
    const int chunk = (E + NBLK - 1) / NBLK;     // 6250

    char* ws = (char*)d_ws;
    size_t off = 0;
    _Float16* h       = (_Float16*)(ws + off); off += align256((size_t)N * 128 * 2);
    uint2*    edges   = (uint2*)   (ws + off); off += align256((size_t)E * 8);
    int*      hist_g  = (int*)     (ws + off); off += align256((size_t)NB * NBLK * 4);
    int*      tot     = (int*)     (ws + off); off += align256((size_t)NB * 4);
    int*      bkt_ptr = (int*)     (ws + off); off += align256((size_t)(NB + 1) * 4);
    _Float16* W16     = (_Float16*)(ws + off); off += align256((size_t)128 * 128 * 2);
    (void)ws_size; (void)n_in; (void)out_size;

    const int gemmB = (N + 127) / 128;           // 782

    bucket_hist<<<NBLK, SCT, 0, stream>>>(A_row, hist_g, E, chunk, NB, W_w, W16);
    scan1_fast<<<(NB + 3) / 4, 256, 0, stream>>>(hist_g, tot, NB);
    scatter_gemm<<<NBLK + gemmB, 1024, 0, stream>>>(A_row, A_col, A_val, tot, hist_g,
                                                    edges, bkt_ptr, E, chunk, NB,
                                                    AX, Wr_w, Wr_b, g_alpha, h, N);
    spmm_fused<<<NB, 256, 0, stream>>>(bkt_ptr, edges, h, W16, W_b, act_alpha,
                                       (float*)d_out, N);
}